// Round 3
// baseline (210.402 us; speedup 1.0000x reference)
//
#include <hip/hip_runtime.h>
#include <stdint.h>

typedef unsigned short u16;
typedef __attribute__((ext_vector_type(8))) short bf16x8;
typedef __attribute__((ext_vector_type(4))) short bf16x4;
typedef __attribute__((ext_vector_type(4))) float f32x4;
typedef __attribute__((ext_vector_type(4))) unsigned short u16x4;

// async global->LDS, 16B per lane, dest = wave-uniform base + lane*16
#define GLD16(gp, lp) __builtin_amdgcn_global_load_lds( \
    (__attribute__((address_space(1))) void*)(void*)(gp), \
    (__attribute__((address_space(3))) void*)(void*)(lp), 16, 0, 0)

__device__ __forceinline__ u16 f2b(float f) {  // fp32 -> bf16 bits, RNE
  union { float f; unsigned u; } v; v.f = f;
  unsigned r = v.u + 0x7FFFu + ((v.u >> 16) & 1u);
  return (u16)(r >> 16);
}

__device__ __forceinline__ float fexp2(float x) {
#if __has_builtin(__builtin_amdgcn_exp2f)
  return __builtin_amdgcn_exp2f(x);
#else
  return exp2f(x);
#endif
}

// ---------------- weights fp32 -> bf16 (proj_w then out_w, one launch) ----
__global__ __launch_bounds__(256) void cvt_kernel(const float* __restrict__ wq_f,
                                                  const float* __restrict__ wo_f,
                                                  u16* __restrict__ wq,
                                                  u16* __restrict__ wo) {
  int i = blockIdx.x * 256 + threadIdx.x;   // 0 .. 262143
  const float* src; u16* dst; int j;
  if (i < 196608) { src = wq_f; dst = wq; j = i; }
  else            { src = wo_f; dst = wo; j = i - 196608; }
  const float4 f = ((const float4*)src)[j];
  u16x4 r; r[0] = f2b(f.x); r[1] = f2b(f.y); r[2] = f2b(f.z); r[3] = f2b(f.w);
  *(u16x4*)(dst + (size_t)j * 4) = r;
}

// ---------------- GroupNorm -> h in strip layout [B, 32g, 1024sp, 16c] ----
// float4 loads (thread = 16 channels x 4 consecutive pixels), fully
// contiguous 128B-per-thread writes (no cross-block line assembly).
__global__ __launch_bounds__(256) void gn_kernel(const float* __restrict__ x,
                                                 const float* __restrict__ gw,
                                                 const float* __restrict__ gb,
                                                 u16* __restrict__ h) {
  const int b = blockIdx.x >> 5, g = blockIdx.x & 31;
  const float* xg = x + ((size_t)(b * 512 + g * 16)) * 1024;
  const int tid = threadIdx.x;
  float4 vals[16];                 // vals[j] = channel j, pixels 4t..4t+3
  float s = 0.f, ss = 0.f;
#pragma unroll
  for (int j = 0; j < 16; j++) {
    const float4 v = ((const float4*)xg)[j * 256 + tid];
    vals[j] = v;
    s  += (v.x + v.y) + (v.z + v.w);
    ss += (v.x * v.x + v.y * v.y) + (v.z * v.z + v.w * v.w);
  }
#pragma unroll
  for (int off = 32; off; off >>= 1) { s += __shfl_down(s, off); ss += __shfl_down(ss, off); }
  __shared__ float red[8];
  const int wid = tid >> 6, lane = tid & 63;
  if (lane == 0) { red[wid] = s; red[4 + wid] = ss; }
  __syncthreads();
  if (tid == 0) {
    float S = red[0] + red[1] + red[2] + red[3];
    float SS = red[4] + red[5] + red[6] + red[7];
    float mean = S * (1.f / 16384.f);
    float var = SS * (1.f / 16384.f) - mean * mean;
    red[0] = mean; red[1] = rsqrtf(var + 1e-5f);
  }
  __syncthreads();
  const float mean = red[0], rs = red[1];
  float sc[16], bi[16];
#pragma unroll
  for (int c = 0; c < 16; c++) { sc[c] = gw[g * 16 + c] * rs; bi[c] = gb[g * 16 + c]; }
  // write pixels 4t..4t+3, 16 channels each: 128B contiguous per thread
  u16* dst = h + ((size_t)(b * 32 + g) * 1024 + 4 * tid) * 16;
#pragma unroll
  for (int e = 0; e < 4; e++) {
    u16 row[16];
#pragma unroll
    for (int j = 0; j < 16; j++) {
      const float v = (e == 0) ? vals[j].x : (e == 1) ? vals[j].y : (e == 2) ? vals[j].z : vals[j].w;
      row[j] = f2b((v - mean) * sc[j] + bi[j]);
    }
    *(bf16x8*)(dst + e * 16) = *(bf16x8*)&row[0];
    *(bf16x8*)(dst + e * 16 + 8) = *(bf16x8*)&row[8];
  }
}

// ---------------- QKV GEMM (v1 structure; A staged from strip-layout h) --
// q,k stored [B,H,S,D]; v stored TRANSPOSED [B,H,D,S].
// q additionally carries log2(e) so attention can use exp2 directly.
__global__ __launch_bounds__(256) void qkv_gemm(const u16* __restrict__ h,
                                                const u16* __restrict__ w,
                                                const float* __restrict__ bias,
                                                u16* __restrict__ q,
                                                u16* __restrict__ k,
                                                u16* __restrict__ v) {
  __shared__ u16 As[128 * 32];
  __shared__ u16 Bs[128 * 32];
  const int b = blockIdx.z;
  const int bm = blockIdx.x;
  const int bn = blockIdx.y;
  const int tid = threadIdx.x, lane = tid & 63, wid = tid >> 6;
  const int wm = wid & 1, wn = wid >> 1;
  // strip layout: h[(b*32+g)*1024 + sp][16]; A rows sp = bm*128 + row
  const u16* gA = h + (size_t)b * 524288 + (size_t)bm * 128 * 16;
  const u16* gB = w + (size_t)bn * 128 * 512;

  const f32x4 fz = {0.f, 0.f, 0.f, 0.f};
  f32x4 acc[4][4];
#pragma unroll
  for (int i = 0; i < 4; i++)
#pragma unroll
    for (int j = 0; j < 4; j++) acc[i][j] = fz;

  const int r0 = lane >> 2;
  const int ch8 = (lane & 3) * 8;

  for (int kt = 0; kt < 16; ++kt) {
    __syncthreads();
    const int chA = kt * 32 + ch8;               // channel of this 16B A-load
    const int gstrip = chA >> 4, rem = chA & 15; // strip, 0 or 8 within strip
#pragma unroll
    for (int j = 0; j < 2; ++j) {
      const int idx = wid * 2 + j;
      const int row = idx * 16 + r0;
      GLD16(gA + (size_t)gstrip * 16384 + (size_t)row * 16 + rem, &As[idx * 512 + lane * 8]);
      GLD16(gB + (size_t)row * 512 + kt * 32 + ch8, &Bs[idx * 512 + lane * 8]);
    }
    __syncthreads();
    bf16x8 af[4], bf[4];
#pragma unroll
    for (int mi = 0; mi < 4; mi++)
      af[mi] = *(const bf16x8*)&As[(wm * 64 + mi * 16 + (lane & 15)) * 32 + (lane >> 4) * 8];
#pragma unroll
    for (int ni = 0; ni < 4; ni++)
      bf[ni] = *(const bf16x8*)&Bs[(wn * 64 + ni * 16 + (lane & 15)) * 32 + (lane >> 4) * 8];
#pragma unroll
    for (int mi = 0; mi < 4; mi++)
#pragma unroll
      for (int ni = 0; ni < 4; ni++)
        acc[mi][ni] = __builtin_amdgcn_mfma_f32_16x16x32_bf16(af[mi], bf[ni], acc[mi][ni], 0, 0, 0);
  }

  const float qscale = 0.51006972f;            // 2^-1.5 * log2(e)
  const float kscale = 0.35355339059327373f;   // 2^-1.5
  const int quad4 = (lane >> 4) << 2;
#pragma unroll
  for (int mi = 0; mi < 4; mi++) {
    const int m = bm * 128 + wm * 64 + mi * 16 + quad4;
#pragma unroll
    for (int ni = 0; ni < 4; ni++) {
      const int n = bn * 128 + wn * 64 + ni * 16 + (lane & 15);
      const int head = n / 192;
      const int rr = n - head * 192;
      const float bi = bias[n];
      const int d = rr & 63;
      if (rr < 128) {
        u16* dst = (rr < 64) ? q : k;
        const float sc = (rr < 64) ? qscale : kscale;
        dst += ((size_t)(b * 8 + head) * 1024 + m) * 64 + d;
#pragma unroll
        for (int r = 0; r < 4; r++)
          dst[(size_t)r * 64] = f2b((acc[mi][ni][r] + bi) * sc);
      } else {
        u16x4 pk;
#pragma unroll
        for (int r = 0; r < 4; r++) pk[r] = f2b(acc[mi][ni][r] + bi);
        *(u16x4*)(v + ((size_t)(b * 8 + head) * 64 + d) * 1024 + m) = pk;
      }
    }
  }
}

// ---------------- flash attention v10: 8-wave / 256-Q-row blocks ----------
__global__ __launch_bounds__(512) void attn_kernel(const u16* __restrict__ q,
                                                   const u16* __restrict__ k,
                                                   const u16* __restrict__ vT,
                                                   u16* __restrict__ o) {
  __shared__ u16 Ks[2][64 * 64];
  __shared__ u16 Vs[2][64 * 64];
  const int bh = blockIdx.x;
  const int qb = blockIdx.y;      // 0..3
  const int tid = threadIdx.x, lane = tid & 63, wid = tid >> 6;   // wid 0..7
  const u16* Q = q + (size_t)bh * 1024 * 64;
  const u16* K = k + (size_t)bh * 1024 * 64;
  const u16* V = vT + (size_t)bh * 64 * 1024;
  const int qrow0 = qb * 256 + wid * 32;
  const int c15 = lane & 15, quad = lane >> 4;
  const int sw = c15 & 7;                  // read-side swizzle component
  const int srow = tid >> 3;               // 0..63
  const int u8g  = tid & 7;                // 8-col group (K) / 8-key group (V)
  const int s7 = srow & 7;
  const int kld = srow * 64 + ((u8g ^ s7) * 8);
  const int ve = 4 * (u8g >> 2) + 2 * (u8g & 1);   // pc0>>1
  const int vc = ((u8g >> 1) & 1) * 4;             // (pc0&1)*4
  const int vld0 = srow * 64 + ((ve ^ s7) * 8) + vc;
  const int vld1 = srow * 64 + (((ve + 1) ^ s7) * 8) + vc;

  bf16x8 qf[2][2];
#pragma unroll
  for (int kk = 0; kk < 2; kk++)
#pragma unroll
    for (int ni = 0; ni < 2; ni++)
      qf[kk][ni] = *(const bf16x8*)(Q + (size_t)(qrow0 + ni * 16 + c15) * 64 + kk * 32 + quad * 8);

  const f32x4 fz = {0.f, 0.f, 0.f, 0.f};
  const float Mshift = 14.4269504089f;     // 10 * log2(e)
  const f32x4 fm = {-Mshift, -Mshift, -Mshift, -Mshift};
  f32x4 oaccT[4][2];               // O^T[d-tile nd][qrow-tile ni]
#pragma unroll
  for (int i = 0; i < 4; i++)
#pragma unroll
    for (int j = 0; j < 2; j++) oaccT[i][j] = fz;
  float lsum[2] = {0.f, 0.f};

  bf16x8 kr, vr;
  kr = *(const bf16x8*)(K + (size_t)srow * 64 + u8g * 8);
  vr = *(const bf16x8*)(V + (size_t)srow * 1024 + u8g * 8);
  {
    u16* Kd = Ks[0]; u16* Vd = Vs[0];
    *(bf16x8*)&Kd[kld] = kr;
    union { bf16x4 h[2]; bf16x8 v; } a; a.v = vr;
    *(bf16x4*)&Vd[vld0] = a.h[0];
    *(bf16x4*)&Vd[vld1] = a.h[1];
  }
  kr = *(const bf16x8*)(K + (size_t)(64 + srow) * 64 + u8g * 8);
  vr = *(const bf16x8*)(V + (size_t)srow * 1024 + 64 + u8g * 8);

  for (int kt = 0; kt < 16; ++kt) {
    __syncthreads();   // publish buf[kt&1]; retire readers of buf[(kt&1)^1]
    const int cur = kt & 1, alt = cur ^ 1;
    if (kt < 15) {
      u16* Kd = Ks[alt]; u16* Vd = Vs[alt];
      *(bf16x8*)&Kd[kld] = kr;
      union { bf16x4 h[2]; bf16x8 v; } a; a.v = vr;
      *(bf16x4*)&Vd[vld0] = a.h[0];
      *(bf16x4*)&Vd[vld1] = a.h[1];
      const int pk2 = (kt + 2) & 15;
      kr = *(const bf16x8*)(K + ((size_t)pk2 * 64 + srow) * 64 + u8g * 8);
      vr = *(const bf16x8*)(V + (size_t)srow * 1024 + pk2 * 64 + u8g * 8);
    }
    const u16* Kc = Ks[cur];
    const u16* Vc = Vs[cur];

    f32x4 sacc[4][2];
#pragma unroll
    for (int i = 0; i < 4; i++)
#pragma unroll
      for (int j = 0; j < 2; j++) sacc[i][j] = fm;
#pragma unroll
    for (int kk = 0; kk < 2; kk++) {
      bf16x8 af[4];
#pragma unroll
      for (int mi = 0; mi < 4; mi++)
        af[mi] = *(const bf16x8*)&Kc[(mi * 16 + c15) * 64 + (((kk * 4 + quad) ^ sw) * 8)];
      __builtin_amdgcn_s_setprio(1);
#pragma unroll
      for (int mi = 0; mi < 4; mi++)
#pragma unroll
        for (int ni = 0; ni < 2; ni++)
          sacc[mi][ni] = __builtin_amdgcn_mfma_f32_16x16x32_bf16(af[mi], qf[kk][ni], sacc[mi][ni], 0, 0, 0);
      __builtin_amdgcn_s_setprio(0);
    }

    unsigned pkd[4][2][2];   // [key-tile mi][ni][dword]
#pragma unroll
    for (int ni = 0; ni < 2; ni++) {
      float ls = 0.f;
#pragma unroll
      for (int mi = 0; mi < 4; mi++) {
        unsigned pu[4];
#pragma unroll
        for (int r = 0; r < 4; r++) {
          const float p = fexp2(sacc[mi][ni][r]);
          ls += p;
          union { float f; unsigned u; } c; c.f = p;
          pu[r] = c.u;
        }
        pkd[mi][ni][0] = __builtin_amdgcn_perm(pu[1], pu[0], 0x07060302u);
        pkd[mi][ni][1] = __builtin_amdgcn_perm(pu[3], pu[2], 0x07060302u);
      }
      lsum[ni] += ls;
    }

#pragma unroll
    for (int mg = 0; mg < 2; mg++) {
      union { unsigned u[4]; bf16x8 v; } bb[2];
#pragma unroll
      for (int ni = 0; ni < 2; ni++) {
        bb[ni].u[0] = pkd[2 * mg][ni][0];     bb[ni].u[1] = pkd[2 * mg][ni][1];
        bb[ni].u[2] = pkd[2 * mg + 1][ni][0]; bb[ni].u[3] = pkd[2 * mg + 1][ni][1];
      }
      bf16x8 aa[4];
#pragma unroll
      for (int nd = 0; nd < 4; nd++)
        aa[nd] = *(const bf16x8*)&Vc[(nd * 16 + c15) * 64 + (((mg * 4 + quad) ^ sw) * 8)];
      __builtin_amdgcn_s_setprio(1);
#pragma unroll
      for (int nd = 0; nd < 4; nd++)
#pragma unroll
        for (int ni = 0; ni < 2; ni++)
          oaccT[nd][ni] = __builtin_amdgcn_mfma_f32_16x16x32_bf16(aa[nd], bb[ni].v, oaccT[nd][ni], 0, 0, 0);
      __builtin_amdgcn_s_setprio(0);
    }
  }

  float iv[2];
#pragma unroll
  for (int ni = 0; ni < 2; ni++) {
    float l = lsum[ni];
    l += __shfl_xor(l, 16);
    l += __shfl_xor(l, 32);
    iv[ni] = 1.f / l;
  }
  const int b = bh >> 3, hh = bh & 7;
#pragma unroll
  for (int ni = 0; ni < 2; ni++) {
    const int row = qrow0 + ni * 16 + c15;
#pragma unroll
    for (int nd = 0; nd < 4; nd++) {
      u16x4 pk4;
#pragma unroll
      for (int r = 0; r < 4; r++) pk4[r] = f2b(oaccT[nd][ni][r] * iv[ni]);
      *(u16x4*)(o + ((size_t)b * 1024 + row) * 512 + hh * 64 + nd * 16 + quad * 4) = pk4;
    }
  }
}

// ---------------- out proj, D[s][c] orientation + float4 residual epilogue -
// A = attn rows (s), B = wo rows (c): D[m=s][n=c]; r-index maps to
// consecutive s -> float4 x-load / out-store at out[b][c][s].
__global__ __launch_bounds__(256) void out_gemm(const u16* __restrict__ attn,
                                                const u16* __restrict__ wo,
                                                const float* __restrict__ ob,
                                                const float* __restrict__ x,
                                                float* __restrict__ out) {
  __shared__ u16 As[128 * 32];
  __shared__ u16 Bs[128 * 32];
  const int b = blockIdx.z;
  const int bm = blockIdx.x;      // s-tile 0..7
  const int bn = blockIdx.y;      // c-tile 0..3
  const int tid = threadIdx.x, lane = tid & 63, wid = tid >> 6;
  const int wm = wid & 1, wn = wid >> 1;
  const u16* gA = attn + ((size_t)b * 1024 + bm * 128) * 512;
  const u16* gB = wo + (size_t)bn * 128 * 512;

  const f32x4 fz = {0.f, 0.f, 0.f, 0.f};
  f32x4 acc[4][4];
#pragma unroll
  for (int i = 0; i < 4; i++)
#pragma unroll
    for (int j = 0; j < 4; j++) acc[i][j] = fz;

  const int r0 = lane >> 2;
  const int ch8 = (lane & 3) * 8;

  for (int kt = 0; kt < 16; ++kt) {
    __syncthreads();
#pragma unroll
    for (int j = 0; j < 2; ++j) {
      const int idx = wid * 2 + j;
      const int row = idx * 16 + r0;
      GLD16(gA + (size_t)row * 512 + kt * 32 + ch8, &As[idx * 512 + lane * 8]);
      GLD16(gB + (size_t)row * 512 + kt * 32 + ch8, &Bs[idx * 512 + lane * 8]);
    }
    __syncthreads();
    bf16x8 af[4], bf[4];
#pragma unroll
    for (int mi = 0; mi < 4; mi++)
      af[mi] = *(const bf16x8*)&As[(wm * 64 + mi * 16 + (lane & 15)) * 32 + (lane >> 4) * 8];
#pragma unroll
    for (int ni = 0; ni < 4; ni++)
      bf[ni] = *(const bf16x8*)&Bs[(wn * 64 + ni * 16 + (lane & 15)) * 32 + (lane >> 4) * 8];
#pragma unroll
    for (int mi = 0; mi < 4; mi++)
#pragma unroll
      for (int ni = 0; ni < 4; ni++)
        acc[mi][ni] = __builtin_amdgcn_mfma_f32_16x16x32_bf16(af[mi], bf[ni], acc[mi][ni], 0, 0, 0);
  }

  const int quad4 = (lane >> 4) << 2;
  const int c15_ = lane & 15;
#pragma unroll
  for (int mi = 0; mi < 4; mi++) {
    const int m = bm * 128 + wm * 64 + mi * 16 + quad4;   // s base (rows m..m+3)
#pragma unroll
    for (int ni = 0; ni < 4; ni++) {
      const int c = bn * 128 + wn * 64 + ni * 16 + c15_;
      const float bo = ob[c];
      const size_t idx = ((size_t)b * 512 + c) * 1024 + m;
      const float4 xv = *(const float4*)(x + idx);
      float4 ov;
      ov.x = acc[mi][ni][0] + bo + xv.x;
      ov.y = acc[mi][ni][1] + bo + xv.y;
      ov.z = acc[mi][ni][2] + bo + xv.z;
      ov.w = acc[mi][ni][3] + bo + xv.w;
      *(float4*)(out + idx) = ov;
    }
  }
}

extern "C" void kernel_launch(void* const* d_in, const int* in_sizes, int n_in,
                              void* d_out, int out_size, void* d_ws, size_t ws_size,
                              hipStream_t stream) {
  const float* x      = (const float*)d_in[0];
  const float* gn_w   = (const float*)d_in[1];
  const float* gn_b   = (const float*)d_in[2];
  const float* proj_w = (const float*)d_in[3];
  const float* proj_b = (const float*)d_in[4];
  const float* out_w  = (const float*)d_in[5];
  const float* out_b  = (const float*)d_in[6];
  float* out = (float*)d_out;

  char* p = (char*)d_ws;
  u16* h    = (u16*)p; p += (size_t)16 * 1024 * 512 * 2;   // strip layout [B,32,1024,16]
  u16* q    = (u16*)p; p += (size_t)16 * 8 * 1024 * 64 * 2;
  u16* k    = (u16*)p; p += (size_t)16 * 8 * 1024 * 64 * 2;
  u16* v    = (u16*)p; p += (size_t)16 * 8 * 1024 * 64 * 2;   // [B,H,D,S]
  u16* attn = (u16*)p; p += (size_t)16 * 1024 * 512 * 2;
  u16* wq   = (u16*)p; p += (size_t)1536 * 512 * 2;
  u16* wo   = (u16*)p; p += (size_t)512 * 512 * 2;

  cvt_kernel<<<1024, 256, 0, stream>>>(proj_w, out_w, wq, wo);
  gn_kernel<<<512, 256, 0, stream>>>(x, gn_w, gn_b, h);
  qkv_gemm<<<dim3(8, 12, 16), 256, 0, stream>>>(h, wq, proj_b, q, k, v);
  attn_kernel<<<dim3(128, 4), 512, 0, stream>>>(q, k, v, attn);
  out_gemm<<<dim3(8, 4, 16), 256, 0, stream>>>(attn, wo, out_b, x, out);
}

// Round 4
// 204.150 us; speedup vs baseline: 1.0306x; 1.0306x over previous
//
#include <hip/hip_runtime.h>
#include <stdint.h>

typedef unsigned short u16;
typedef __attribute__((ext_vector_type(8))) short bf16x8;
typedef __attribute__((ext_vector_type(4))) short bf16x4;
typedef __attribute__((ext_vector_type(4))) float f32x4;
typedef __attribute__((ext_vector_type(4))) unsigned short u16x4;

// async global->LDS, 16B per lane, dest = wave-uniform base + lane*16
#define GLD16(gp, lp) __builtin_amdgcn_global_load_lds( \
    (__attribute__((address_space(1))) void*)(void*)(gp), \
    (__attribute__((address_space(3))) void*)(void*)(lp), 16, 0, 0)

__device__ __forceinline__ u16 f2b(float f) {  // fp32 -> bf16 bits, RNE
  union { float f; unsigned u; } v; v.f = f;
  unsigned r = v.u + 0x7FFFu + ((v.u >> 16) & 1u);
  return (u16)(r >> 16);
}

__device__ __forceinline__ float fexp2(float x) {
#if __has_builtin(__builtin_amdgcn_exp2f)
  return __builtin_amdgcn_exp2f(x);
#else
  return exp2f(x);
#endif
}

// ---------------- fused: GroupNorm (blocks 0..511) + weight cvt (512..1535) ----
// gn -> h in strip layout [B, 32g, 1024sp, 16c]; float4 loads, 128B/thread
// contiguous writes. cvt: proj_w then out_w fp32->bf16.
__global__ __launch_bounds__(256) void gncvt_kernel(const float* __restrict__ x,
                                                    const float* __restrict__ gw,
                                                    const float* __restrict__ gb,
                                                    u16* __restrict__ h,
                                                    const float* __restrict__ wq_f,
                                                    const float* __restrict__ wo_f,
                                                    u16* __restrict__ wq,
                                                    u16* __restrict__ wo) {
  if (blockIdx.x >= 512) {
    int i = (blockIdx.x - 512) * 256 + threadIdx.x;   // 0 .. 262143
    const float* src; u16* dst; int j;
    if (i < 196608) { src = wq_f; dst = wq; j = i; }
    else            { src = wo_f; dst = wo; j = i - 196608; }
    const float4 f = ((const float4*)src)[j];
    u16x4 r; r[0] = f2b(f.x); r[1] = f2b(f.y); r[2] = f2b(f.z); r[3] = f2b(f.w);
    *(u16x4*)(dst + (size_t)j * 4) = r;
    return;
  }
  const int b = blockIdx.x >> 5, g = blockIdx.x & 31;
  const float* xg = x + ((size_t)(b * 512 + g * 16)) * 1024;
  const int tid = threadIdx.x;
  float4 vals[16];                 // vals[j] = channel j, pixels 4t..4t+3
  float s = 0.f, ss = 0.f;
#pragma unroll
  for (int j = 0; j < 16; j++) {
    const float4 v = ((const float4*)xg)[j * 256 + tid];
    vals[j] = v;
    s  += (v.x + v.y) + (v.z + v.w);
    ss += (v.x * v.x + v.y * v.y) + (v.z * v.z + v.w * v.w);
  }
#pragma unroll
  for (int off = 32; off; off >>= 1) { s += __shfl_down(s, off); ss += __shfl_down(ss, off); }
  __shared__ float red[8];
  const int wid = tid >> 6, lane = tid & 63;
  if (lane == 0) { red[wid] = s; red[4 + wid] = ss; }
  __syncthreads();
  if (tid == 0) {
    float S = red[0] + red[1] + red[2] + red[3];
    float SS = red[4] + red[5] + red[6] + red[7];
    float mean = S * (1.f / 16384.f);
    float var = SS * (1.f / 16384.f) - mean * mean;
    red[0] = mean; red[1] = rsqrtf(var + 1e-5f);
  }
  __syncthreads();
  const float mean = red[0], rs = red[1];
  float sc[16], bi[16];
#pragma unroll
  for (int c = 0; c < 16; c++) { sc[c] = gw[g * 16 + c] * rs; bi[c] = gb[g * 16 + c]; }
  u16* dst = h + ((size_t)(b * 32 + g) * 1024 + 4 * tid) * 16;
#pragma unroll
  for (int e = 0; e < 4; e++) {
    u16 row[16];
#pragma unroll
    for (int j = 0; j < 16; j++) {
      const float v = (e == 0) ? vals[j].x : (e == 1) ? vals[j].y : (e == 2) ? vals[j].z : vals[j].w;
      row[j] = f2b((v - mean) * sc[j] + bi[j]);
    }
    *(bf16x8*)(dst + e * 16) = *(bf16x8*)&row[0];
    *(bf16x8*)(dst + e * 16 + 8) = *(bf16x8*)&row[8];
  }
}

// ---------------- QKV GEMM v3: 256x256 tile, BK=64, fat 128x64 wave-tiles --
// M=16384, N=1536, K=512. grid (64,6)=384 blocks, 512 thr = 8 waves (2M x 4N),
// per-wave output 128x64, acc[8][4]. LDS = 2dbuf x (A 32KB + B 32KB) = 128KB
// -> 1 block/CU, 2 waves/SIMD. Rationale: LDS bytes/MFMA drops 768 -> 500
// (fat wave-tiles re-read less), the structural wall of the 128^2 kernels.
// Sync: ONE s_barrier + one AGED vmcnt(0) per K-tile. All 8 GLD16s for tile
// t+1 issue at tile-t top; by the wait they are ~2 MFMA phases (600+ cyc) old
// => counted-wait semantics (T4) without bookkeeping. Race-free: buf d's
// previous readers (tile t-1) finished before the barrier that ended t-1.
// XOR involution swizzle (proven 0-conflict in v2): phys 16B chunk p holds
// logical chunk p^(row&7); reads use ((kk*4+quad)^(c15&7)).
__global__ __launch_bounds__(512, 2) void qkv_gemm(const u16* __restrict__ h,
                                                   const u16* __restrict__ w,
                                                   const float* __restrict__ bias,
                                                   u16* __restrict__ q,
                                                   u16* __restrict__ k,
                                                   u16* __restrict__ v) {
  __shared__ u16 As[2][256 * 64];   // 64 KB
  __shared__ u16 Bs[2][256 * 64];   // 64 KB
  const int bm = blockIdx.x;        // 0..63
  const int bn = blockIdx.y;        // 0..5
  const int tid = threadIdx.x, lane = tid & 63, wid = tid >> 6;
  const int wm = wid & 1, wn = wid >> 1;     // 2M x 4N waves, 128x64 each
  const int c15 = lane & 15, quad = lane >> 4;
  const int sw = c15 & 7;                    // read-side swizzle
  const int b = bm >> 2;                     // batch (256 | 1024)
  const int sp0 = (bm & 3) * 256;            // row base within batch

  // staging: load i in 0..3 covers slot = i*512+tid -> (row = slot>>3,
  // phys-chunk pc = tid&7); source logical chunk lc = pc ^ (row&7) with
  // row&7 = (tid>>3)&7 (i*64 and sp0 are multiples of 8).
  const int t8 = tid >> 3;
  const int lc = (tid & 7) ^ (t8 & 7);
  // A source (strip layout h[b][g][sp][16]): channel c0 = kt*64 + lc*8
  const u16* pA = h + (size_t)b * 524288 + (size_t)(lc >> 1) * 16384
                + (size_t)(sp0 + t8) * 16 + (lc & 1) * 8;
  const u16* pB = w + (size_t)(bn * 256 + t8) * 512 + lc * 8;

  const f32x4 fz = {0.f, 0.f, 0.f, 0.f};
  f32x4 acc[8][4];
#pragma unroll
  for (int i = 0; i < 8; i++)
#pragma unroll
    for (int j = 0; j < 4; j++) acc[i][j] = fz;

  // prologue: stage K-tile 0 into buffer 0, wait, publish
#pragma unroll
  for (int i = 0; i < 4; i++) {
    GLD16(pA + (size_t)i * 1024, &As[0][(i * 512 + tid) * 8]);
    GLD16(pB + (size_t)i * 32768, &Bs[0][(i * 512 + tid) * 8]);
  }
  asm volatile("s_waitcnt vmcnt(0)" ::: "memory");
  __builtin_amdgcn_s_barrier();
  __builtin_amdgcn_sched_barrier(0);

  for (int kt = 0; kt < 8; ++kt) {
    const int cb = kt & 1, db = cb ^ 1;
    // issue next tile's 8 loads FIRST (they age across both MFMA phases)
    if (kt < 7) {
#pragma unroll
      for (int i = 0; i < 4; i++) {
        GLD16(pA + (size_t)(kt + 1) * 65536 + (size_t)i * 1024, &As[db][(i * 512 + tid) * 8]);
        GLD16(pB + (size_t)(kt + 1) * 64 + (size_t)i * 32768, &Bs[db][(i * 512 + tid) * 8]);
      }
      __builtin_amdgcn_sched_barrier(0);
    }
    // B frags (all 4 n-tiles x 2 k-halves), held across both phases
    bf16x8 bfx[2][4];
#pragma unroll
    for (int kk = 0; kk < 2; kk++) {
      const int kc = ((kk * 4 + quad) ^ sw) * 8;
#pragma unroll
      for (int ni = 0; ni < 4; ni++)
        bfx[kk][ni] = *(const bf16x8*)&Bs[cb][(wn * 64 + ni * 16 + c15) * 64 + kc];
    }
#pragma unroll
    for (int ph = 0; ph < 2; ph++) {
      bf16x8 af[2][4];
#pragma unroll
      for (int kk = 0; kk < 2; kk++) {
        const int kc = ((kk * 4 + quad) ^ sw) * 8;
#pragma unroll
        for (int mi = 0; mi < 4; mi++)
          af[kk][mi] = *(const bf16x8*)&As[cb][(wm * 128 + ph * 64 + mi * 16 + c15) * 64 + kc];
      }
      __builtin_amdgcn_s_setprio(1);
#pragma unroll
      for (int kk = 0; kk < 2; kk++)
#pragma unroll
        for (int mi = 0; mi < 4; mi++)
#pragma unroll
          for (int ni = 0; ni < 4; ni++)
            acc[ph * 4 + mi][ni] = __builtin_amdgcn_mfma_f32_16x16x32_bf16(af[kk][mi], bfx[kk][ni], acc[ph * 4 + mi][ni], 0, 0, 0);
      __builtin_amdgcn_s_setprio(0);
    }
    asm volatile("s_waitcnt vmcnt(0)" ::: "memory");   // aged ~2 phases: ~free
    __builtin_amdgcn_s_barrier();                      // publish buf db
    __builtin_amdgcn_sched_barrier(0);
  }

  const float qscale = 0.51006972f;            // 2^-1.5 * log2(e)
  const float kscale = 0.35355339059327373f;   // 2^-1.5
  const int quad4 = quad << 2;
#pragma unroll
  for (int mi = 0; mi < 8; mi++) {
    const int sp = sp0 + wm * 128 + mi * 16 + quad4;   // row within batch
#pragma unroll
    for (int ni = 0; ni < 4; ni++) {
      const int n = bn * 256 + wn * 64 + ni * 16 + c15;
      const int head = n / 192;
      const int rr = n - head * 192;
      const float bi = bias[n];
      const int d = rr & 63;
      if (rr < 128) {
        u16* dst = (rr < 64) ? q : k;
        const float sc = (rr < 64) ? qscale : kscale;
        dst += ((size_t)(b * 8 + head) * 1024 + sp) * 64 + d;
#pragma unroll
        for (int r = 0; r < 4; r++)
          dst[(size_t)r * 64] = f2b((acc[mi][ni][r] + bi) * sc);
      } else {
        u16x4 pk;
#pragma unroll
        for (int r = 0; r < 4; r++) pk[r] = f2b(acc[mi][ni][r] + bi);
        *(u16x4*)(v + ((size_t)(b * 8 + head) * 64 + d) * 1024 + sp) = pk;
      }
    }
  }
}

// ---------------- flash attention v10: 8-wave / 256-Q-row blocks ----------
__global__ __launch_bounds__(512) void attn_kernel(const u16* __restrict__ q,
                                                   const u16* __restrict__ k,
                                                   const u16* __restrict__ vT,
                                                   u16* __restrict__ o) {
  __shared__ u16 Ks[2][64 * 64];
  __shared__ u16 Vs[2][64 * 64];
  const int bh = blockIdx.x;
  const int qb = blockIdx.y;      // 0..3
  const int tid = threadIdx.x, lane = tid & 63, wid = tid >> 6;   // wid 0..7
  const u16* Q = q + (size_t)bh * 1024 * 64;
  const u16* K = k + (size_t)bh * 1024 * 64;
  const u16* V = vT + (size_t)bh * 64 * 1024;
  const int qrow0 = qb * 256 + wid * 32;
  const int c15 = lane & 15, quad = lane >> 4;
  const int sw = c15 & 7;                  // read-side swizzle component
  const int srow = tid >> 3;               // 0..63
  const int u8g  = tid & 7;                // 8-col group (K) / 8-key group (V)
  const int s7 = srow & 7;
  const int kld = srow * 64 + ((u8g ^ s7) * 8);
  const int ve = 4 * (u8g >> 2) + 2 * (u8g & 1);   // pc0>>1
  const int vc = ((u8g >> 1) & 1) * 4;             // (pc0&1)*4
  const int vld0 = srow * 64 + ((ve ^ s7) * 8) + vc;
  const int vld1 = srow * 64 + (((ve + 1) ^ s7) * 8) + vc;

  bf16x8 qf[2][2];
#pragma unroll
  for (int kk = 0; kk < 2; kk++)
#pragma unroll
    for (int ni = 0; ni < 2; ni++)
      qf[kk][ni] = *(const bf16x8*)(Q + (size_t)(qrow0 + ni * 16 + c15) * 64 + kk * 32 + quad * 8);

  const f32x4 fz = {0.f, 0.f, 0.f, 0.f};
  const float Mshift = 14.4269504089f;     // 10 * log2(e)
  const f32x4 fm = {-Mshift, -Mshift, -Mshift, -Mshift};
  f32x4 oaccT[4][2];               // O^T[d-tile nd][qrow-tile ni]
#pragma unroll
  for (int i = 0; i < 4; i++)
#pragma unroll
    for (int j = 0; j < 2; j++) oaccT[i][j] = fz;
  float lsum[2] = {0.f, 0.f};

  bf16x8 kr, vr;
  kr = *(const bf16x8*)(K + (size_t)srow * 64 + u8g * 8);
  vr = *(const bf16x8*)(V + (size_t)srow * 1024 + u8g * 8);
  {
    u16* Kd = Ks[0]; u16* Vd = Vs[0];
    *(bf16x8*)&Kd[kld] = kr;
    union { bf16x4 h[2]; bf16x8 v; } a; a.v = vr;
    *(bf16x4*)&Vd[vld0] = a.h[0];
    *(bf16x4*)&Vd[vld1] = a.h[1];
  }
  kr = *(const bf16x8*)(K + (size_t)(64 + srow) * 64 + u8g * 8);
  vr = *(const bf16x8*)(V + (size_t)srow * 1024 + 64 + u8g * 8);

  for (int kt = 0; kt < 16; ++kt) {
    __syncthreads();   // publish buf[kt&1]; retire readers of buf[(kt&1)^1]
    const int cur = kt & 1, alt = cur ^ 1;
    if (kt < 15) {
      u16* Kd = Ks[alt]; u16* Vd = Vs[alt];
      *(bf16x8*)&Kd[kld] = kr;
      union { bf16x4 h[2]; bf16x8 v; } a; a.v = vr;
      *(bf16x4*)&Vd[vld0] = a.h[0];
      *(bf16x4*)&Vd[vld1] = a.h[1];
      const int pk2 = (kt + 2) & 15;
      kr = *(const bf16x8*)(K + ((size_t)pk2 * 64 + srow) * 64 + u8g * 8);
      vr = *(const bf16x8*)(V + (size_t)srow * 1024 + pk2 * 64 + u8g * 8);
    }
    const u16* Kc = Ks[cur];
    const u16* Vc = Vs[cur];

    f32x4 sacc[4][2];
#pragma unroll
    for (int i = 0; i < 4; i++)
#pragma unroll
      for (int j = 0; j < 2; j++) sacc[i][j] = fm;
#pragma unroll
    for (int kk = 0; kk < 2; kk++) {
      bf16x8 af[4];
#pragma unroll
      for (int mi = 0; mi < 4; mi++)
        af[mi] = *(const bf16x8*)&Kc[(mi * 16 + c15) * 64 + (((kk * 4 + quad) ^ sw) * 8)];
      __builtin_amdgcn_s_setprio(1);
#pragma unroll
      for (int mi = 0; mi < 4; mi++)
#pragma unroll
        for (int ni = 0; ni < 2; ni++)
          sacc[mi][ni] = __builtin_amdgcn_mfma_f32_16x16x32_bf16(af[mi], qf[kk][ni], sacc[mi][ni], 0, 0, 0);
      __builtin_amdgcn_s_setprio(0);
    }

    unsigned pkd[4][2][2];   // [key-tile mi][ni][dword]
#pragma unroll
    for (int ni = 0; ni < 2; ni++) {
      float ls = 0.f;
#pragma unroll
      for (int mi = 0; mi < 4; mi++) {
        unsigned pu[4];
#pragma unroll
        for (int r = 0; r < 4; r++) {
          const float p = fexp2(sacc[mi][ni][r]);
          ls += p;
          union { float f; unsigned u; } c; c.f = p;
          pu[r] = c.u;
        }
        pkd[mi][ni][0] = __builtin_amdgcn_perm(pu[1], pu[0], 0x07060302u);
        pkd[mi][ni][1] = __builtin_amdgcn_perm(pu[3], pu[2], 0x07060302u);
      }
      lsum[ni] += ls;
    }

#pragma unroll
    for (int mg = 0; mg < 2; mg++) {
      union { unsigned u[4]; bf16x8 v; } bb[2];
#pragma unroll
      for (int ni = 0; ni < 2; ni++) {
        bb[ni].u[0] = pkd[2 * mg][ni][0];     bb[ni].u[1] = pkd[2 * mg][ni][1];
        bb[ni].u[2] = pkd[2 * mg + 1][ni][0]; bb[ni].u[3] = pkd[2 * mg + 1][ni][1];
      }
      bf16x8 aa[4];
#pragma unroll
      for (int nd = 0; nd < 4; nd++)
        aa[nd] = *(const bf16x8*)&Vc[(nd * 16 + c15) * 64 + (((mg * 4 + quad) ^ sw) * 8)];
      __builtin_amdgcn_s_setprio(1);
#pragma unroll
      for (int nd = 0; nd < 4; nd++)
#pragma unroll
        for (int ni = 0; ni < 2; ni++)
          oaccT[nd][ni] = __builtin_amdgcn_mfma_f32_16x16x32_bf16(aa[nd], bb[ni].v, oaccT[nd][ni], 0, 0, 0);
      __builtin_amdgcn_s_setprio(0);
    }
  }

  float iv[2];
#pragma unroll
  for (int ni = 0; ni < 2; ni++) {
    float l = lsum[ni];
    l += __shfl_xor(l, 16);
    l += __shfl_xor(l, 32);
    iv[ni] = 1.f / l;
  }
  const int b = bh >> 3, hh = bh & 7;
#pragma unroll
  for (int ni = 0; ni < 2; ni++) {
    const int row = qrow0 + ni * 16 + c15;
#pragma unroll
    for (int nd = 0; nd < 4; nd++) {
      u16x4 pk4;
#pragma unroll
      for (int r = 0; r < 4; r++) pk4[r] = f2b(oaccT[nd][ni][r] * iv[ni]);
      *(u16x4*)(o + ((size_t)b * 1024 + row) * 512 + hh * 64 + nd * 16 + quad * 4) = pk4;
    }
  }
}

// ---------------- out proj, D[s][c] orientation + float4 residual epilogue -
__global__ __launch_bounds__(256) void out_gemm(const u16* __restrict__ attn,
                                                const u16* __restrict__ wo,
                                                const float* __restrict__ ob,
                                                const float* __restrict__ x,
                                                float* __restrict__ out) {
  __shared__ u16 As[128 * 32];
  __shared__ u16 Bs[128 * 32];
  const int b = blockIdx.z;
  const int bm = blockIdx.x;      // s-tile 0..7
  const int bn = blockIdx.y;      // c-tile 0..3
  const int tid = threadIdx.x, lane = tid & 63, wid = tid >> 6;
  const int wm = wid & 1, wn = wid >> 1;
  const u16* gA = attn + ((size_t)b * 1024 + bm * 128) * 512;
  const u16* gB = wo + (size_t)bn * 128 * 512;

  const f32x4 fz = {0.f, 0.f, 0.f, 0.f};
  f32x4 acc[4][4];
#pragma unroll
  for (int i = 0; i < 4; i++)
#pragma unroll
    for (int j = 0; j < 4; j++) acc[i][j] = fz;

  const int r0 = lane >> 2;
  const int ch8 = (lane & 3) * 8;

  for (int kt = 0; kt < 16; ++kt) {
    __syncthreads();
#pragma unroll
    for (int j = 0; j < 2; ++j) {
      const int idx = wid * 2 + j;
      const int row = idx * 16 + r0;
      GLD16(gA + (size_t)row * 512 + kt * 32 + ch8, &As[idx * 512 + lane * 8]);
      GLD16(gB + (size_t)row * 512 + kt * 32 + ch8, &Bs[idx * 512 + lane * 8]);
    }
    __syncthreads();
    bf16x8 af[4], bf[4];
#pragma unroll
    for (int mi = 0; mi < 4; mi++)
      af[mi] = *(const bf16x8*)&As[(wm * 64 + mi * 16 + (lane & 15)) * 32 + (lane >> 4) * 8];
#pragma unroll
    for (int ni = 0; ni < 4; ni++)
      bf[ni] = *(const bf16x8*)&Bs[(wn * 64 + ni * 16 + (lane & 15)) * 32 + (lane >> 4) * 8];
#pragma unroll
    for (int mi = 0; mi < 4; mi++)
#pragma unroll
      for (int ni = 0; ni < 4; ni++)
        acc[mi][ni] = __builtin_amdgcn_mfma_f32_16x16x32_bf16(af[mi], bf[ni], acc[mi][ni], 0, 0, 0);
  }

  const int quad4 = (lane >> 4) << 2;
  const int c15_ = lane & 15;
#pragma unroll
  for (int mi = 0; mi < 4; mi++) {
    const int m = bm * 128 + wm * 64 + mi * 16 + quad4;   // s base (rows m..m+3)
#pragma unroll
    for (int ni = 0; ni < 4; ni++) {
      const int c = bn * 128 + wn * 64 + ni * 16 + c15_;
      const float bo = ob[c];
      const size_t idx = ((size_t)b * 512 + c) * 1024 + m;
      const float4 xv = *(const float4*)(x + idx);
      float4 ov;
      ov.x = acc[mi][ni][0] + bo + xv.x;
      ov.y = acc[mi][ni][1] + bo + xv.y;
      ov.z = acc[mi][ni][2] + bo + xv.z;
      ov.w = acc[mi][ni][3] + bo + xv.w;
      *(float4*)(out + idx) = ov;
    }
  }
}

extern "C" void kernel_launch(void* const* d_in, const int* in_sizes, int n_in,
                              void* d_out, int out_size, void* d_ws, size_t ws_size,
                              hipStream_t stream) {
  const float* x      = (const float*)d_in[0];
  const float* gn_w   = (const float*)d_in[1];
  const float* gn_b   = (const float*)d_in[2];
  const float* proj_w = (const float*)d_in[3];
  const float* proj_b = (const float*)d_in[4];
  const float* out_w  = (const float*)d_in[5];
  const float* out_b  = (const float*)d_in[6];
  float* out = (float*)d_out;

  char* p = (char*)d_ws;
  u16* h    = (u16*)p; p += (size_t)16 * 1024 * 512 * 2;   // strip layout [B,32,1024,16]
  u16* q    = (u16*)p; p += (size_t)16 * 8 * 1024 * 64 * 2;
  u16* k    = (u16*)p; p += (size_t)16 * 8 * 1024 * 64 * 2;
  u16* v    = (u16*)p; p += (size_t)16 * 8 * 1024 * 64 * 2;   // [B,H,D,S]
  u16* attn = (u16*)p; p += (size_t)16 * 1024 * 512 * 2;
  u16* wq   = (u16*)p; p += (size_t)1536 * 512 * 2;
  u16* wo   = (u16*)p; p += (size_t)512 * 512 * 2;

  gncvt_kernel<<<1536, 256, 0, stream>>>(x, gn_w, gn_b, h, proj_w, out_w, wq, wo);
  qkv_gemm<<<dim3(64, 6), 512, 0, stream>>>(h, wq, proj_b, q, k, v);
  attn_kernel<<<dim3(128, 4), 512, 0, stream>>>(q, k, v, attn);
  out_gemm<<<dim3(8, 4, 16), 256, 0, stream>>>(attn, wo, out_b, x, out);
}

// Round 5
// 195.759 us; speedup vs baseline: 1.0748x; 1.0429x over previous
//
#include <hip/hip_runtime.h>
#include <stdint.h>

typedef unsigned short u16;
typedef __attribute__((ext_vector_type(8))) short bf16x8;
typedef __attribute__((ext_vector_type(4))) short bf16x4;
typedef __attribute__((ext_vector_type(4))) float f32x4;
typedef __attribute__((ext_vector_type(4))) unsigned short u16x4;

// async global->LDS, 16B per lane, dest = wave-uniform base + lane*16
#define GLD16(gp, lp) __builtin_amdgcn_global_load_lds( \
    (__attribute__((address_space(1))) void*)(void*)(gp), \
    (__attribute__((address_space(3))) void*)(void*)(lp), 16, 0, 0)

__device__ __forceinline__ u16 f2b(float f) {  // fp32 -> bf16 bits, RNE
  union { float f; unsigned u; } v; v.f = f;
  unsigned r = v.u + 0x7FFFu + ((v.u >> 16) & 1u);
  return (u16)(r >> 16);
}

__device__ __forceinline__ float fexp2(float x) {
#if __has_builtin(__builtin_amdgcn_exp2f)
  return __builtin_amdgcn_exp2f(x);
#else
  return exp2f(x);
#endif
}

// ============================ LDS-image layouts ============================
// h_img[mt 0..63][kt 0..15][256r x 4chunks]: panel = 8192 u16 (16 KB).
//   slot(r, c8, j) = r*32 + ((c8 ^ ((r>>1)&3))*8) + j    (c8 = 8-ch chunk)
// w_img[nt 0..15][kt 0..15][96r x 4chunks]: panel = 3072 u16 (6 KB), same
//   per-row swizzle. Staging a panel = flat GLD16 copy (1 KB/wave-instr).
// ===========================================================================

// ---------------- fused: GroupNorm (blocks 0..511) + weight cvt (512..1535)
__global__ __launch_bounds__(256) void gncvt_kernel(const float* __restrict__ x,
                                                    const float* __restrict__ gw,
                                                    const float* __restrict__ gb,
                                                    u16* __restrict__ h,
                                                    const float* __restrict__ wq_f,
                                                    const float* __restrict__ wo_f,
                                                    u16* __restrict__ wq,
                                                    u16* __restrict__ wo) {
  if (blockIdx.x >= 512) {
    int i = (blockIdx.x - 512) * 256 + threadIdx.x;   // 0 .. 262143
    if (i < 196608) {
      // proj_w -> w_img: row n = i>>7, channels c0 = (i&127)*4
      const float4 f = ((const float4*)wq_f)[i];
      const int n = i >> 7, c0 = (i & 127) * 4;
      const int nt = n / 96, r = n - nt * 96;
      const int kt = c0 >> 5, c8 = (c0 >> 3) & 3, wi = c0 & 7;
      const int sel = (r >> 1) & 3;
      u16x4 rr; rr[0] = f2b(f.x); rr[1] = f2b(f.y); rr[2] = f2b(f.z); rr[3] = f2b(f.w);
      *(u16x4*)(wq + (size_t)(nt * 16 + kt) * 3072 + r * 32 + ((c8 ^ sel) * 8) + wi) = rr;
    } else {
      int j = i - 196608;
      const float4 f = ((const float4*)wo_f)[j];
      u16x4 rr; rr[0] = f2b(f.x); rr[1] = f2b(f.y); rr[2] = f2b(f.z); rr[3] = f2b(f.w);
      *(u16x4*)(wo + (size_t)j * 4) = rr;
    }
    return;
  }
  const int b = blockIdx.x >> 5, g = blockIdx.x & 31;
  const float* xg = x + ((size_t)(b * 512 + g * 16)) * 1024;
  const int tid = threadIdx.x;
  float4 vals[16];                 // vals[j] = channel j, pixels 4t..4t+3
  float s = 0.f, ss = 0.f;
#pragma unroll
  for (int j = 0; j < 16; j++) {
    const float4 v = ((const float4*)xg)[j * 256 + tid];
    vals[j] = v;
    s  += (v.x + v.y) + (v.z + v.w);
    ss += (v.x * v.x + v.y * v.y) + (v.z * v.z + v.w * v.w);
  }
#pragma unroll
  for (int off = 32; off; off >>= 1) { s += __shfl_down(s, off); ss += __shfl_down(ss, off); }
  __shared__ float red[8];
  const int wid = tid >> 6, lane = tid & 63;
  if (lane == 0) { red[wid] = s; red[4 + wid] = ss; }
  __syncthreads();
  if (tid == 0) {
    float S = red[0] + red[1] + red[2] + red[3];
    float SS = red[4] + red[5] + red[6] + red[7];
    float mean = S * (1.f / 16384.f);
    float var = SS * (1.f / 16384.f) - mean * mean;
    red[0] = mean; red[1] = rsqrtf(var + 1e-5f);
  }
  __syncthreads();
  const float mean = red[0], rs = red[1];
  float sc[16], bi[16];
#pragma unroll
  for (int c = 0; c < 16; c++) { sc[c] = gw[g * 16 + c] * rs; bi[c] = gb[g * 16 + c]; }
  // write into h_img: this block owns chunks {2(g&1), 2(g&1)+1} of kt = g>>1
  const int mt = b * 4 + (tid >> 6);
  const int kt = g >> 1, c8a = (g & 1) * 2;
  u16* base = h + (size_t)(mt * 16 + kt) * 8192;
#pragma unroll
  for (int e = 0; e < 4; e++) {
    const int r = (tid & 63) * 4 + e;
    const int sel = (r >> 1) & 3;
    u16 row[16];
#pragma unroll
    for (int j = 0; j < 16; j++) {
      const float v = (e == 0) ? vals[j].x : (e == 1) ? vals[j].y : (e == 2) ? vals[j].z : vals[j].w;
      row[j] = f2b((v - mean) * sc[j] + bi[j]);
    }
    *(bf16x8*)(base + r * 32 + ((c8a ^ sel) * 8)) = *(bf16x8*)&row[0];
    *(bf16x8*)(base + r * 32 + (((c8a + 1) ^ sel) * 8)) = *(bf16x8*)&row[8];
  }
}

// ---------------- QKV GEMM v4: LDS-image staging, 256x96 tile, BK=32 ------
// M=16384, N=1536, K=512. grid (64,16)=1024 blocks; 512 thr = 8 waves
// (4M x 2N, wave 64x48, acc[4][3]); LDS 44 KB + VGPR<=128 -> 2 blocks/CU,
// exactly 2 full rounds. Staging = flat GLD16 panel copies (1 KB contiguous
// per wave-instr: A 2/thread, B 1/thread for tid<384) -> minimal TA
// transactions, zero address math. Per-row XOR swizzle baked into the image;
// reads use chunk = quad ^ ((c15>>1)&3) (2-way max = free). One aged
// vmcnt(0) + s_barrier per K-tile; co-resident block hides the stall.
__global__ __launch_bounds__(512, 4) void qkv_gemm(const u16* __restrict__ h,
                                                   const u16* __restrict__ w,
                                                   const float* __restrict__ bias,
                                                   u16* __restrict__ q,
                                                   u16* __restrict__ k,
                                                   u16* __restrict__ v) {
  __shared__ u16 As[2][8192];   // 2 x 16 KB
  __shared__ u16 Bs[2][3072];   // 2 x 6 KB
  const int bm = blockIdx.x;    // 0..63  (256 rows)
  const int bn = blockIdx.y;    // 0..15  (96 cols)
  const int tid = threadIdx.x, lane = tid & 63, wid = tid >> 6;
  const int wm = wid >> 1, wn = wid & 1;     // 4M x 2N waves, 64x48 each
  const int c15 = lane & 15, quad = lane >> 4;
  const int kc = ((quad ^ ((c15 >> 1) & 3)) * 8);   // phys chunk offset (u16)

  const u16* pA = h + (size_t)bm * 16 * 8192 + (size_t)tid * 8;   // + kt*8192
  const u16* pB = w + (size_t)bn * 16 * 3072 + (size_t)tid * 8;   // + kt*3072
  const bool doB = (tid < 384);

  const f32x4 fz = {0.f, 0.f, 0.f, 0.f};
  f32x4 acc[4][3];
#pragma unroll
  for (int i = 0; i < 4; i++)
#pragma unroll
    for (int j = 0; j < 3; j++) acc[i][j] = fz;

  // prologue: stage kt=0 into buf 0
  GLD16(pA, &As[0][tid * 8]);
  GLD16(pA + 4096, &As[0][4096 + tid * 8]);
  if (doB) GLD16(pB, &Bs[0][tid * 8]);
  asm volatile("s_waitcnt vmcnt(0)" ::: "memory");
  __builtin_amdgcn_s_barrier();
  __builtin_amdgcn_sched_barrier(0);

  for (int kt = 0; kt < 16; ++kt) {
    const int cb = kt & 1, db = cb ^ 1;
    if (kt < 15) {   // issue next panel first; ages across this tile's MFMAs
      const u16* nA = pA + (size_t)(kt + 1) * 8192;
      GLD16(nA, &As[db][tid * 8]);
      GLD16(nA + 4096, &As[db][4096 + tid * 8]);
      if (doB) GLD16(pB + (size_t)(kt + 1) * 3072, &Bs[db][tid * 8]);
      __builtin_amdgcn_sched_barrier(0);
    }
    bf16x8 af[4], bf[3];
#pragma unroll
    for (int mi = 0; mi < 4; mi++)
      af[mi] = *(const bf16x8*)&As[cb][(wm * 64 + mi * 16 + c15) * 32 + kc];
#pragma unroll
    for (int ni = 0; ni < 3; ni++)
      bf[ni] = *(const bf16x8*)&Bs[cb][(wn * 48 + ni * 16 + c15) * 32 + kc];
    __builtin_amdgcn_s_setprio(1);
#pragma unroll
    for (int mi = 0; mi < 4; mi++)
#pragma unroll
      for (int ni = 0; ni < 3; ni++)
        acc[mi][ni] = __builtin_amdgcn_mfma_f32_16x16x32_bf16(af[mi], bf[ni], acc[mi][ni], 0, 0, 0);
    __builtin_amdgcn_s_setprio(0);
    asm volatile("s_waitcnt vmcnt(0)" ::: "memory");   // aged ~full tile
    __builtin_amdgcn_s_barrier();
    __builtin_amdgcn_sched_barrier(0);
  }

  const float qscale = 0.51006972f;            // 2^-1.5 * log2(e)
  const float kscale = 0.35355339059327373f;   // 2^-1.5
  const int b = bm >> 2;
  const int quad4 = quad << 2;
#pragma unroll
  for (int mi = 0; mi < 4; mi++) {
    const int sp = (bm & 3) * 256 + wm * 64 + mi * 16 + quad4;
#pragma unroll
    for (int ni = 0; ni < 3; ni++) {
      const int n = bn * 96 + wn * 48 + ni * 16 + c15;
      const int head = n / 192;
      const int rr = n - head * 192;
      const float bi = bias[n];
      const int d = rr & 63;
      if (rr < 128) {
        u16* dst = (rr < 64) ? q : k;
        const float sc = (rr < 64) ? qscale : kscale;
        dst += ((size_t)(b * 8 + head) * 1024 + sp) * 64 + d;
#pragma unroll
        for (int r = 0; r < 4; r++)
          dst[(size_t)r * 64] = f2b((acc[mi][ni][r] + bi) * sc);
      } else {
        u16x4 pk;
#pragma unroll
        for (int r = 0; r < 4; r++) pk[r] = f2b(acc[mi][ni][r] + bi);
        *(u16x4*)(v + ((size_t)(b * 8 + head) * 64 + d) * 1024 + sp) = pk;
      }
    }
  }
}

// ---------------- flash attention v10: 8-wave / 256-Q-row blocks ----------
__global__ __launch_bounds__(512) void attn_kernel(const u16* __restrict__ q,
                                                   const u16* __restrict__ k,
                                                   const u16* __restrict__ vT,
                                                   u16* __restrict__ o) {
  __shared__ u16 Ks[2][64 * 64];
  __shared__ u16 Vs[2][64 * 64];
  const int bh = blockIdx.x;
  const int qb = blockIdx.y;      // 0..3
  const int tid = threadIdx.x, lane = tid & 63, wid = tid >> 6;   // wid 0..7
  const u16* Q = q + (size_t)bh * 1024 * 64;
  const u16* K = k + (size_t)bh * 1024 * 64;
  const u16* V = vT + (size_t)bh * 64 * 1024;
  const int qrow0 = qb * 256 + wid * 32;
  const int c15 = lane & 15, quad = lane >> 4;
  const int sw = c15 & 7;                  // read-side swizzle component
  const int srow = tid >> 3;               // 0..63
  const int u8g  = tid & 7;                // 8-col group (K) / 8-key group (V)
  const int s7 = srow & 7;
  const int kld = srow * 64 + ((u8g ^ s7) * 8);
  const int ve = 4 * (u8g >> 2) + 2 * (u8g & 1);   // pc0>>1
  const int vc = ((u8g >> 1) & 1) * 4;             // (pc0&1)*4
  const int vld0 = srow * 64 + ((ve ^ s7) * 8) + vc;
  const int vld1 = srow * 64 + (((ve + 1) ^ s7) * 8) + vc;

  bf16x8 qf[2][2];
#pragma unroll
  for (int kk = 0; kk < 2; kk++)
#pragma unroll
    for (int ni = 0; ni < 2; ni++)
      qf[kk][ni] = *(const bf16x8*)(Q + (size_t)(qrow0 + ni * 16 + c15) * 64 + kk * 32 + quad * 8);

  const f32x4 fz = {0.f, 0.f, 0.f, 0.f};
  const float Mshift = 14.4269504089f;     // 10 * log2(e)
  const f32x4 fm = {-Mshift, -Mshift, -Mshift, -Mshift};
  f32x4 oaccT[4][2];               // O^T[d-tile nd][qrow-tile ni]
#pragma unroll
  for (int i = 0; i < 4; i++)
#pragma unroll
    for (int j = 0; j < 2; j++) oaccT[i][j] = fz;
  float lsum[2] = {0.f, 0.f};

  bf16x8 kr, vr;
  kr = *(const bf16x8*)(K + (size_t)srow * 64 + u8g * 8);
  vr = *(const bf16x8*)(V + (size_t)srow * 1024 + u8g * 8);
  {
    u16* Kd = Ks[0]; u16* Vd = Vs[0];
    *(bf16x8*)&Kd[kld] = kr;
    union { bf16x4 h[2]; bf16x8 v; } a; a.v = vr;
    *(bf16x4*)&Vd[vld0] = a.h[0];
    *(bf16x4*)&Vd[vld1] = a.h[1];
  }
  kr = *(const bf16x8*)(K + (size_t)(64 + srow) * 64 + u8g * 8);
  vr = *(const bf16x8*)(V + (size_t)srow * 1024 + 64 + u8g * 8);

  for (int kt = 0; kt < 16; ++kt) {
    __syncthreads();   // publish buf[kt&1]; retire readers of buf[(kt&1)^1]
    const int cur = kt & 1, alt = cur ^ 1;
    if (kt < 15) {
      u16* Kd = Ks[alt]; u16* Vd = Vs[alt];
      *(bf16x8*)&Kd[kld] = kr;
      union { bf16x4 h[2]; bf16x8 v; } a; a.v = vr;
      *(bf16x4*)&Vd[vld0] = a.h[0];
      *(bf16x4*)&Vd[vld1] = a.h[1];
      const int pk2 = (kt + 2) & 15;
      kr = *(const bf16x8*)(K + ((size_t)pk2 * 64 + srow) * 64 + u8g * 8);
      vr = *(const bf16x8*)(V + (size_t)srow * 1024 + pk2 * 64 + u8g * 8);
    }
    const u16* Kc = Ks[cur];
    const u16* Vc = Vs[cur];

    f32x4 sacc[4][2];
#pragma unroll
    for (int i = 0; i < 4; i++)
#pragma unroll
      for (int j = 0; j < 2; j++) sacc[i][j] = fm;
#pragma unroll
    for (int kk = 0; kk < 2; kk++) {
      bf16x8 af[4];
#pragma unroll
      for (int mi = 0; mi < 4; mi++)
        af[mi] = *(const bf16x8*)&Kc[(mi * 16 + c15) * 64 + (((kk * 4 + quad) ^ sw) * 8)];
      __builtin_amdgcn_s_setprio(1);
#pragma unroll
      for (int mi = 0; mi < 4; mi++)
#pragma unroll
        for (int ni = 0; ni < 2; ni++)
          sacc[mi][ni] = __builtin_amdgcn_mfma_f32_16x16x32_bf16(af[mi], qf[kk][ni], sacc[mi][ni], 0, 0, 0);
      __builtin_amdgcn_s_setprio(0);
    }

    unsigned pkd[4][2][2];   // [key-tile mi][ni][dword]
#pragma unroll
    for (int ni = 0; ni < 2; ni++) {
      float ls = 0.f;
#pragma unroll
      for (int mi = 0; mi < 4; mi++) {
        unsigned pu[4];
#pragma unroll
        for (int r = 0; r < 4; r++) {
          const float p = fexp2(sacc[mi][ni][r]);
          ls += p;
          union { float f; unsigned u; } c; c.f = p;
          pu[r] = c.u;
        }
        pkd[mi][ni][0] = __builtin_amdgcn_perm(pu[1], pu[0], 0x07060302u);
        pkd[mi][ni][1] = __builtin_amdgcn_perm(pu[3], pu[2], 0x07060302u);
      }
      lsum[ni] += ls;
    }

#pragma unroll
    for (int mg = 0; mg < 2; mg++) {
      union { unsigned u[4]; bf16x8 v; } bb[2];
#pragma unroll
      for (int ni = 0; ni < 2; ni++) {
        bb[ni].u[0] = pkd[2 * mg][ni][0];     bb[ni].u[1] = pkd[2 * mg][ni][1];
        bb[ni].u[2] = pkd[2 * mg + 1][ni][0]; bb[ni].u[3] = pkd[2 * mg + 1][ni][1];
      }
      bf16x8 aa[4];
#pragma unroll
      for (int nd = 0; nd < 4; nd++)
        aa[nd] = *(const bf16x8*)&Vc[(nd * 16 + c15) * 64 + (((mg * 4 + quad) ^ sw) * 8)];
      __builtin_amdgcn_s_setprio(1);
#pragma unroll
      for (int nd = 0; nd < 4; nd++)
#pragma unroll
        for (int ni = 0; ni < 2; ni++)
          oaccT[nd][ni] = __builtin_amdgcn_mfma_f32_16x16x32_bf16(aa[nd], bb[ni].v, oaccT[nd][ni], 0, 0, 0);
      __builtin_amdgcn_s_setprio(0);
    }
  }

  float iv[2];
#pragma unroll
  for (int ni = 0; ni < 2; ni++) {
    float l = lsum[ni];
    l += __shfl_xor(l, 16);
    l += __shfl_xor(l, 32);
    iv[ni] = 1.f / l;
  }
  const int b = bh >> 3, hh = bh & 7;
#pragma unroll
  for (int ni = 0; ni < 2; ni++) {
    const int row = qrow0 + ni * 16 + c15;
#pragma unroll
    for (int nd = 0; nd < 4; nd++) {
      u16x4 pk4;
#pragma unroll
      for (int r = 0; r < 4; r++) pk4[r] = f2b(oaccT[nd][ni][r] * iv[ni]);
      *(u16x4*)(o + ((size_t)b * 1024 + row) * 512 + hh * 64 + nd * 16 + quad * 4) = pk4;
    }
  }
}

// ---------------- out proj, D[s][c] orientation + float4 residual epilogue -
__global__ __launch_bounds__(256) void out_gemm(const u16* __restrict__ attn,
                                                const u16* __restrict__ wo,
                                                const float* __restrict__ ob,
                                                const float* __restrict__ x,
                                                float* __restrict__ out) {
  __shared__ u16 As[128 * 32];
  __shared__ u16 Bs[128 * 32];
  const int b = blockIdx.z;
  const int bm = blockIdx.x;      // s-tile 0..7
  const int bn = blockIdx.y;      // c-tile 0..3
  const int tid = threadIdx.x, lane = tid & 63, wid = tid >> 6;
  const int wm = wid & 1, wn = wid >> 1;
  const u16* gA = attn + ((size_t)b * 1024 + bm * 128) * 512;
  const u16* gB = wo + (size_t)bn * 128 * 512;

  const f32x4 fz = {0.f, 0.f, 0.f, 0.f};
  f32x4 acc[4][4];
#pragma unroll
  for (int i = 0; i < 4; i++)
#pragma unroll
    for (int j = 0; j < 4; j++) acc[i][j] = fz;

  const int r0 = lane >> 2;
  const int ch8 = (lane & 3) * 8;

  for (int kt = 0; kt < 16; ++kt) {
    __syncthreads();
#pragma unroll
    for (int j = 0; j < 2; ++j) {
      const int idx = wid * 2 + j;
      const int row = idx * 16 + r0;
      GLD16(gA + (size_t)row * 512 + kt * 32 + ch8, &As[idx * 512 + lane * 8]);
      GLD16(gB + (size_t)row * 512 + kt * 32 + ch8, &Bs[idx * 512 + lane * 8]);
    }
    __syncthreads();
    bf16x8 af[4], bf[4];
#pragma unroll
    for (int mi = 0; mi < 4; mi++)
      af[mi] = *(const bf16x8*)&As[(wm * 64 + mi * 16 + (lane & 15)) * 32 + (lane >> 4) * 8];
#pragma unroll
    for (int ni = 0; ni < 4; ni++)
      bf[ni] = *(const bf16x8*)&Bs[(wn * 64 + ni * 16 + (lane & 15)) * 32 + (lane >> 4) * 8];
#pragma unroll
    for (int mi = 0; mi < 4; mi++)
#pragma unroll
      for (int ni = 0; ni < 4; ni++)
        acc[mi][ni] = __builtin_amdgcn_mfma_f32_16x16x32_bf16(af[mi], bf[ni], acc[mi][ni], 0, 0, 0);
  }

  const int quad4 = (lane >> 4) << 2;
  const int c15_ = lane & 15;
#pragma unroll
  for (int mi = 0; mi < 4; mi++) {
    const int m = bm * 128 + wm * 64 + mi * 16 + quad4;   // s base (rows m..m+3)
#pragma unroll
    for (int ni = 0; ni < 4; ni++) {
      const int c = bn * 128 + wn * 64 + ni * 16 + c15_;
      const float bo = ob[c];
      const size_t idx = ((size_t)b * 512 + c) * 1024 + m;
      const float4 xv = *(const float4*)(x + idx);
      float4 ov;
      ov.x = acc[mi][ni][0] + bo + xv.x;
      ov.y = acc[mi][ni][1] + bo + xv.y;
      ov.z = acc[mi][ni][2] + bo + xv.z;
      ov.w = acc[mi][ni][3] + bo + xv.w;
      *(float4*)(out + idx) = ov;
    }
  }
}

extern "C" void kernel_launch(void* const* d_in, const int* in_sizes, int n_in,
                              void* d_out, int out_size, void* d_ws, size_t ws_size,
                              hipStream_t stream) {
  const float* x      = (const float*)d_in[0];
  const float* gn_w   = (const float*)d_in[1];
  const float* gn_b   = (const float*)d_in[2];
  const float* proj_w = (const float*)d_in[3];
  const float* proj_b = (const float*)d_in[4];
  const float* out_w  = (const float*)d_in[5];
  const float* out_b  = (const float*)d_in[6];
  float* out = (float*)d_out;

  char* p = (char*)d_ws;
  u16* h    = (u16*)p; p += (size_t)16 * 1024 * 512 * 2;   // h_img [64mt][16kt][8192]
  u16* q    = (u16*)p; p += (size_t)16 * 8 * 1024 * 64 * 2;
  u16* k    = (u16*)p; p += (size_t)16 * 8 * 1024 * 64 * 2;
  u16* v    = (u16*)p; p += (size_t)16 * 8 * 1024 * 64 * 2;   // [B,H,D,S]
  u16* attn = (u16*)p; p += (size_t)16 * 1024 * 512 * 2;
  u16* wq   = (u16*)p; p += (size_t)1536 * 512 * 2;           // w_img [16nt][16kt][3072]
  u16* wo   = (u16*)p; p += (size_t)512 * 512 * 2;

  gncvt_kernel<<<1536, 256, 0, stream>>>(x, gn_w, gn_b, h, proj_w, out_w, wq, wo);
  qkv_gemm<<<dim3(64, 16), 512, 0, stream>>>(h, wq, proj_b, q, k, v);
  attn_kernel<<<dim3(128, 4), 512, 0, stream>>>(q, k, v, attn);
  out_gemm<<<dim3(8, 4, 16), 256, 0, stream>>>(attn, wo, out_b, x, out);
}